// Round 1
// 670.070 us; speedup vs baseline: 1.0073x; 1.0073x over previous
//
#include <hip/hip_runtime.h>

#define ROWS 8192
#define COLS 16384
#define BLOCK 256
#define WPB (BLOCK / 64)     // waves per block = 4
#define GRID (ROWS / WPB)    // 2048 blocks -> one wave per row, whole grid resident
                             // (8 blocks/CU x 256 CU, 32 waves/CU = max occupancy)

// Kernel 1: one WAVE per row. Row = 16384 floats = 4096 float4 = 64 float4/lane.
// No LDS, no __syncthreads in the hot path: stream + shuffle-tree + 1 store/wave.
__global__ __launch_bounds__(BLOCK) void row_hinge_kernel(const float* __restrict__ B,
                                                          float* __restrict__ ws) {
    const int wave = threadIdx.x >> 6;
    const int lane = threadIdx.x & 63;
    const int row  = blockIdx.x * WPB + wave;
    const float4* rowp = (const float4*)(B + (size_t)row * COLS);

    float s = 0.0f;
    // 64 iterations; unroll 8 -> 8 float4 (32 VGPRs) in flight per wave,
    // 8 KB/wave x 32 waves/CU = 256 KB/CU in flight >> latency-BW product.
#pragma unroll 8
    for (int it = 0; it < (COLS / 4) / 64; ++it) {
        float4 v = rowp[lane + it * 64];
        s += (v.x + v.y) + (v.z + v.w);
    }

    // wave-64 shuffle reduction
#pragma unroll
    for (int off = 32; off > 0; off >>= 1)
        s += __shfl_down(s, off, 64);

    if (lane == 0) {
        float h = s - 1.0f;
        ws[row] = h > 0.0f ? h : 0.0f;
    }
}

// Kernel 2: reduce 8192 hinges -> mean -> out[0]. Single block, vectorized,
// deterministic (no atomics, keeps absmax tight).
__global__ __launch_bounds__(BLOCK) void final_reduce_kernel(const float* __restrict__ ws,
                                                             float* __restrict__ out) {
    const int tid = threadIdx.x;
    const float4* p = (const float4*)ws;  // ROWS/4 = 2048 float4
    float s = 0.0f;
#pragma unroll
    for (int it = 0; it < (ROWS / 4) / BLOCK; ++it) {  // 8 iterations
        float4 v = p[tid + it * BLOCK];
        s += (v.x + v.y) + (v.z + v.w);
    }

#pragma unroll
    for (int off = 32; off > 0; off >>= 1)
        s += __shfl_down(s, off, 64);

    __shared__ float wsum[BLOCK / 64];
    const int wave = tid >> 6;
    const int lane = tid & 63;
    if (lane == 0) wsum[wave] = s;
    __syncthreads();

    if (tid == 0) {
        float total = 0.0f;
#pragma unroll
        for (int w = 0; w < BLOCK / 64; ++w) total += wsum[w];
        out[0] = total * (1.0f / (float)ROWS);  // PENALTY_B = 1.0
    }
}

extern "C" void kernel_launch(void* const* d_in, const int* in_sizes, int n_in,
                              void* d_out, int out_size, void* d_ws, size_t ws_size,
                              hipStream_t stream) {
    const float* B = (const float*)d_in[0];
    float* out = (float*)d_out;
    float* ws = (float*)d_ws;  // needs ROWS*4 = 32 KiB

    row_hinge_kernel<<<GRID, BLOCK, 0, stream>>>(B, ws);
    final_reduce_kernel<<<1, BLOCK, 0, stream>>>(ws, out);
}